// Round 1
// 99.316 us; speedup vs baseline: 1.0008x; 1.0008x over previous
//
#include <hip/hip_runtime.h>
#include <stdint.h>
#include <stddef.h>

// MambaMesh random-walk + gather-recenter.  R10: two walks per wave.
// PRNG (bit-exact vs JAX partitionable Threefry, verified R1-R8, absmax 0.0):
//   split(key,n)[j]        = threefry2x32(key; 0, j)   (both output words)
//   random_bits(key,32,()) = xor-fold of threefry2x32(key; 0, 0)
// R9 result: LDS-bitmap visited (43.2us kernel). Counters: VALUBusy 61%,
// HBM 3%, conflicts negligible -> walk loop is VALU-ISSUE-bound on
// wave-uniform machinery (64 lanes advance ONE walk). R10 pairs walks:
// lanes 0-31 = walk A, lanes 32-63 = walk B -> the SAME ~100-instr/iter
// stream advances TWO walks (all state becomes half-uniform; 9 broadcast
// ds_reads become 2-address broadcasts = free 2-way aliasing, m136).
//   block = 512 thr = 8 waves = 16 walks; 256 blocks; LDS unchanged
//   162,816 B (table 6*NMAX + 16 bitmaps) -> still 1 block/CU, all CUs.
// seq held as 2 regs/lane (positions hl, hl+32); shuffles index own half
// via (j&31)|(lane&32); need/backtrack is half-uniform so every __shfl in
// divergent regions sources a fully-active half. Fallback (!lds_ok, unused
// in harness): two sequential full-wave walks with the R5/R8-verified code.

namespace {

__device__ __forceinline__ uint32_t rotl32(uint32_t x, int r) {
  return (x << r) | (x >> (32 - r));
}

// Threefry-2x32, 20 rounds — exactly JAX's threefry2x32_p.
__device__ __forceinline__ void tf2x32(uint32_t ka, uint32_t kb,
                                       uint32_t x0, uint32_t x1,
                                       uint32_t& o0, uint32_t& o1) {
  const uint32_t kc = ka ^ kb ^ 0x1BD11BDAu;
  x0 += ka; x1 += kb;
#define TF_R4(r0, r1, r2, r3)                          \
  x0 += x1; x1 = rotl32(x1, r0); x1 ^= x0;             \
  x0 += x1; x1 = rotl32(x1, r1); x1 ^= x0;             \
  x0 += x1; x1 = rotl32(x1, r2); x1 ^= x0;             \
  x0 += x1; x1 = rotl32(x1, r3); x1 ^= x0;
  TF_R4(13, 15, 26, 6)  x0 += kb; x1 += kc + 1u;
  TF_R4(17, 29, 16, 24) x0 += kc; x1 += ka + 2u;
  TF_R4(13, 15, 26, 6)  x0 += ka; x1 += kb + 3u;
  TF_R4(17, 29, 16, 24) x0 += kb; x1 += kc + 4u;
  TF_R4(13, 15, 26, 6)  x0 += kc; x1 += ka + 5u;
#undef TF_R4
  o0 = x0; o1 = x1;
}

// (hi, lo) bits of jax.random.randint(key, (), 0, span): span-independent.
__device__ __forceinline__ void randbits(uint32_t ka, uint32_t kb,
                                         uint32_t& hi, uint32_t& lo) {
  uint32_t s0a, s0b, s1a, s1b, h0, h1;
  tf2x32(ka, kb, 0u, 0u, s0a, s0b);   // split(key)[0]
  tf2x32(ka, kb, 0u, 1u, s1a, s1b);   // split(key)[1]
  tf2x32(s0a, s0b, 0u, 0u, h0, h1);
  hi = h0 ^ h1;
  tf2x32(s1a, s1b, 0u, 0u, h0, h1);
  lo = h0 ^ h1;
}

__device__ __forceinline__ uint32_t r_generic(uint32_t hi, uint32_t lo,
                                              uint32_t span) {
  uint32_t mult = 65536u % span;
  mult = (mult * mult) % span;
  return ((hi % span) * mult + (lo % span)) % span;
}

// pick code: r3 (span=3 result) in bits 0..1, r2 (span=2 result) in bit 2.
__device__ __forceinline__ uint32_t pick_code(uint32_t hi, uint32_t lo) {
  return ((hi % 3u + lo % 3u) % 3u) | ((lo & 1u) << 2);
}

constexpr int WAVES = 8;      // waves per block (512 threads)
constexpr int WPB = 16;       // walks per block = 2 per wave
constexpr int CH = 64;        // cached chain length (covers seq_len 63)
constexpr int NMAX = 20352;   // LDS-table capacity (rows)
constexpr int VISW = 636;     // bitmap words per walk = ceil(NMAX/32)

__global__ __launch_bounds__(512) void walk_kernel(
    const float* __restrict__ xyz, const int* __restrict__ nbrs,
    const int* __restrict__ centers, const int* __restrict__ n_faces_p,
    const int* __restrict__ seq_len_p, float* __restrict__ out,
    int s0, int num_walks, int Lp1) {
  // Static LDS: 81,408 + 40,704 + 40,704 = 162,816 B (HW max 163,840).
  __shared__ uint32_t nb01L[NMAX];        // n0 | n1<<16
  __shared__ uint16_t nb2L[NMAX];         // n2
  __shared__ uint32_t visL[WPB * VISW];   // bitmaps; pre-zero: keys scratch

  const int tid = threadIdx.x;
  const int wv = tid >> 6, lane = tid & 63;
  const int hl = lane & 31;               // lane within half-wave
  const int hb = lane & 32;               // half base for shuffles
  const int w0 = blockIdx.x * WPB;
  if (w0 >= num_walks) return;             // block-uniform

  const int N = *n_faces_p;
  const int L = *seq_len_p;
  const int B = s0 / (3 * N);
  const int G = num_walks / B;
  const bool lds_ok = (N <= NMAX) && (G % WPB == 0);   // grid-uniform

  // ---- Phase A0: wave 0 = 16 carry chains (keys -> visL scratch);
  //      waves 1..7 = table staging (lds_ok only). -------------------------
  if (wv == 0) {
    if (lane < WPB && (w0 + lane) < num_walks) {
      uint32_t ka, kb;
      tf2x32(0u, 42u, 0u, (uint32_t)(w0 + lane), ka, kb);  // k_0
      visL[(lane * CH + 0) * 2 + 0] = ka;
      visL[(lane * CH + 0) * 2 + 1] = kb;
#pragma clang loop unroll(disable)
      for (int c2 = 1; c2 < CH; ++c2) {
        tf2x32(ka, kb, 0u, 0u, ka, kb);
        visL[(lane * CH + c2) * 2 + 0] = ka;
        visL[(lane * CH + c2) * 2 + 1] = kb;
      }
    }
  } else if (lds_ok) {
    const int bb0 = w0 / G;                // block's 16 walks share a batch
    const int* __restrict__ nbT = nbrs + (size_t)bb0 * N * 3;
    for (int r = tid - 64; r < N; r += (WAVES - 1) * 64) {
      const int3 v = *reinterpret_cast<const int3*>(nbT + 3 * (size_t)r);
      nb01L[r] = (uint32_t)v.x | ((uint32_t)v.y << 16);
      nb2L[r]  = (uint16_t)v.z;
    }
  }
  __syncthreads();   // barrier 1: keys + table staged

  if (lds_ok) {
    // =================== paired half-wave walks ===========================
    const int kw = 2 * wv + (hb >> 5);     // this half's walk slot in block
    const int w = w0 + kw;
    const bool act0 = (w < num_walks);     // half-uniform
    const int bb = (act0 ? w : w0) / G;
    const float* __restrict__ xb = xyz + (size_t)bb * N * 3;
    const int f0 = act0 ? centers[w] : 0;

    // Per-step keys: lane hl holds k_{hl} (mk*0) and k_{hl+32} (mk*1) of
    // its half's walk.
    const uint32_t mka0 = visL[(kw * CH + hl) * 2 + 0];
    const uint32_t mkb0 = visL[(kw * CH + hl) * 2 + 1];
    const uint32_t mka1 = visL[(kw * CH + hl + 32) * 2 + 0];
    const uint32_t mkb1 = visL[(kw * CH + hl + 32) * 2 + 1];
    uint32_t mycode0, mycode1;
    {
      uint32_t k1a, k1b, hi, lo;
      tf2x32(mka0, mkb0, 0u, 1u, k1a, k1b);   // k1 = split(k,4)[1]
      randbits(k1a, k1b, hi, lo);
      mycode0 = pick_code(hi, lo);
      tf2x32(mka1, mkb1, 0u, 1u, k1a, k1b);
      randbits(k1a, k1b, hi, lo);
      mycode1 = pick_code(hi, lo);
    }
    __syncthreads();   // barrier 2: all scratch reads done; bitmaps reusable

    uint32_t extka = 0, extkb = 0;
    int extc = -1;     // lazy chain extension beyond CH (only after backtracks)
    auto get_key = [&](int idxk, uint32_t& ra, uint32_t& rb) {
      // idxk is wave-uniform at every call site.
      if (idxk < CH) {
        const int sidx = (idxk & 31) | hb;
        const uint32_t sa = (idxk < 32) ? mka0 : mka1;
        const uint32_t sb = (idxk < 32) ? mkb0 : mkb1;
        ra = (uint32_t)__shfl((int)sa, sidx);
        rb = (uint32_t)__shfl((int)sb, sidx);
      } else {
        if (extc < 0) {
          extka = (uint32_t)__shfl((int)mka1, 31 | hb);
          extkb = (uint32_t)__shfl((int)mkb1, 31 | hb);
          extc = CH - 1;
        }
        while (extc < idxk) { tf2x32(extka, extkb, 0u, 0u, extka, extkb); ++extc; }
        ra = extka; rb = extkb;
      }
    };

    uint32_t* __restrict__ visW = visL + kw * VISW;
    // Half-local zero of OWN bitmap (in-order DS; no barrier needed).
    for (int j = hl; j < VISW; j += 32) visW[j] = 0u;
    if (hl == 0) visW[(unsigned)f0 >> 5] = 1u << (f0 & 31);

    uint32_t p0 = nb01L[f0];
    int n0 = (int)(p0 & 0xffffu), n1 = (int)(p0 >> 16), n2 = (int)nb2L[f0];
    int seqr0 = (hl == 0) ? f0 : -1;        // seq[hl]
    int seqr1 = -1;                         // seq[hl+32]
    uint32_t code_next = (uint32_t)__shfl((int)mycode0, hb);
    int i = act0 ? 1 : (L + 1);
    int bs = 1, c = 0;

    while (__any(i <= L)) {
      const bool act = (i <= L);
      const int idx = c; ++c;
      // 9 LDS reads issued together (<=2 addrs each: free 2-way broadcast).
      const uint32_t pA = nb01L[n0]; const uint32_t a2 = nb2L[n0];
      const uint32_t pB = nb01L[n1]; const uint32_t b2 = nb2L[n1];
      const uint32_t pC = nb01L[n2]; const uint32_t c2v = nb2L[n2];
      const uint32_t wv0 = visW[(unsigned)n0 >> 5];
      const uint32_t wv1 = visW[(unsigned)n1 >> 5];
      const uint32_t wv2 = visW[(unsigned)n2 >> 5];
      const uint32_t codeP = code_next;
      {
        const int cc = (c < CH) ? c : 0;    // wave-uniform
        const uint32_t csrc = (cc < 32) ? mycode0 : mycode1;
        code_next = (uint32_t)__shfl((int)csrc, (cc & 31) | hb);
      }

      const uint32_t u0 = ((wv0 >> (n0 & 31)) & 1u) ^ 1u;
      const uint32_t u1 = ((wv1 >> (n1 & 31)) & 1u) ^ 1u;
      const uint32_t u2 = ((wv2 >> (n2 & 31)) & 1u) ^ 1u;
      const uint32_t cnt = u0 + u1 + u2;
      const bool need = act && (cnt == 0);

      if (__builtin_expect(__any(need), 0)) {
        // ---- rare path: handles both halves generically ----
        uint32_t kia, kib;
        get_key(idx, kia, kib);             // full-exec; idx uniform
        // common-path candidate for act&&!need lanes
        uint32_t code = codeP;
        if (idx >= CH) {
          uint32_t k1a, k1b, hi, lo;
          tf2x32(kia, kib, 0u, 1u, k1a, k1b);
          randbits(k1a, k1b, hi, lo);
          code = pick_code(hi, lo);
        }
        const uint32_t r3c = code & 3u, r2c = (code >> 2) & 1u;
        const uint32_t tgt = (cnt == 3 ? r3c : (cnt == 2 ? r2c : 0)) + 1;
        const int selc = (u0 == tgt) ? 0 : ((u0 + u1 == tgt) ? 1 : 2);
        const int to_add_c = (selc == 0) ? n0 : ((selc == 1) ? n1 : n2);

        // backtrack for needy half(s); need is half-uniform so every __shfl
        // below sources its own fully-active half.
        bool found = false;
        int ta = 0, bsc = bs;
        if (need) {
          uint32_t kka, kkb;
          tf2x32(kia, kib, 0u, 2u, kka, kkb);  // k2
          while (!found && i > bsc) {
            uint32_t ca, cb, kpa, kpb;
            tf2x32(kka, kkb, 0u, 0u, ca, cb);
            tf2x32(kka, kkb, 0u, 1u, kpa, kpb);
            const int j = i - bsc - 1;
            const int sidx = (j & 31) | hb;
            const int bk0 = __shfl(seqr0, sidx);
            const int bk1 = __shfl(seqr1, sidx);
            const int back = (j < 32) ? bk0 : bk1;
            const uint32_t pm = nb01L[back];
            const int m0 = (int)(pm & 0xffffu), m1 = (int)(pm >> 16);
            const int m2 = (int)nb2L[back];
            const uint32_t e0 = ((visW[(unsigned)m0 >> 5] >> (m0 & 31)) & 1u) ^ 1u;
            const uint32_t e1 = ((visW[(unsigned)m1 >> 5] >> (m1 & 31)) & 1u) ^ 1u;
            const uint32_t e2 = ((visW[(unsigned)m2 >> 5] >> (m2 & 31)) & 1u) ^ 1u;
            const uint32_t bc = e0 + e1 + e2;
            if (bc > 0) {
              uint32_t bhi, blo;
              randbits(kpa, kpb, bhi, blo);
              const uint32_t bcode = pick_code(bhi, blo);
              const uint32_t br3 = bcode & 3u, br2 = (bcode >> 2) & 1u;
              const uint32_t t2v = (bc == 3 ? br3 : (bc == 2 ? br2 : 0)) + 1;
              ta = (e0 == t2v) ? m0 : ((e0 + e1 == t2v) ? m1 : m2);
              found = true;
            } else {
              bsc += 2;
            }
            kka = ca; kkb = cb;
          }
        }
        int rnd = 0;
        if (need && !found) {               // shfl-free: safe divergent
          uint32_t k3a, k3b, rhi, rlo;
          tf2x32(kia, kib, 0u, 3u, k3a, k3b);  // k3
          randbits(k3a, k3b, rhi, rlo);
          rnd = (int)r_generic(rhi, rlo, (uint32_t)N);
        }
        const bool hit = need && found;
        const int to_add = need ? (found ? ta : rnd) : to_add_c;
        const int i_new = hit ? (i - bsc) : i;
        // splat range [i_new, i) on successful backtrack
        seqr0 = (hit && hl >= i_new && hl < i) ? to_add : seqr0;
        seqr1 = (hit && (hl + 32) >= i_new && (hl + 32) < i) ? to_add : seqr1;
        bs = act ? (hit ? bsc : 1) : bs;
        i = i_new;
        if (act && hl == 0) {               // set bit (fresh read, in-order DS)
          const uint32_t wd = visW[(unsigned)to_add >> 5];
          visW[(unsigned)to_add >> 5] = wd | (1u << (to_add & 31));
        }
        seqr0 = (act && hl == i) ? to_add : seqr0;
        seqr1 = (act && (hl + 32) == i) ? to_add : seqr1;
        if (act) ++i;
        const int sf = act ? to_add : 0;
        const uint32_t p = nb01L[sf];
        if (act) {
          n0 = (int)(p & 0xffffu); n1 = (int)(p >> 16); n2 = (int)nb2L[sf];
        }
        continue;
      }
      // ---- common path: branch-lean; all act lanes have cnt>0 ----
      uint32_t code = codeP;
      if (__builtin_expect(idx >= CH, 0)) {   // live tree beyond cached steps
        uint32_t ia, ib, k1a, k1b, hi, lo;
        get_key(idx, ia, ib);
        tf2x32(ia, ib, 0u, 1u, k1a, k1b);
        randbits(k1a, k1b, hi, lo);
        code = pick_code(hi, lo);
      }
      const uint32_t r3 = code & 3u, r2 = (code >> 2) & 1u;
      const uint32_t target = (cnt == 3 ? r3 : (cnt == 2 ? r2 : 0)) + 1;
      const int sel = (u0 == target) ? 0 : ((u0 + u1 == target) ? 1 : 2);
      const int to_add = (sel == 0) ? n0 : ((sel == 1) ? n1 : n2);
      // set bit: reuse the word read this iter (includes last iter's write).
      const uint32_t wsel = (sel == 0) ? wv0 : ((sel == 1) ? wv1 : wv2);
      if (act && hl == 0)
        visW[(unsigned)to_add >> 5] = wsel | (1u << (to_add & 31));
      seqr0 = (act && hl == i) ? to_add : seqr0;
      seqr1 = (act && (hl + 32) == i) ? to_add : seqr1;
      if (act) { bs = 1; ++i; }
      if (sel == 0)      { n0 = (int)(pA & 0xffffu); n1 = (int)(pA >> 16); n2 = (int)a2; }
      else if (sel == 1) { n0 = (int)(pB & 0xffffu); n1 = (int)(pB >> 16); n2 = (int)b2; }
      else               { n0 = (int)(pC & 0xffffu); n1 = (int)(pC >> 16); n2 = (int)c2v; }
    }

    // ---- Epilogue: lane hl holds seq[hl] and seq[hl+32] -----------------
    if (act0) {
      const float cx = xb[3 * (size_t)f0 + 0];
      const float cy = xb[3 * (size_t)f0 + 1];
      const float cz = xb[3 * (size_t)f0 + 2];
      if (hl < Lp1) {
        const int node = seqr0;
        float3 v;
        v.x = xb[3 * (size_t)node + 0] - cx;
        v.y = xb[3 * (size_t)node + 1] - cy;
        v.z = xb[3 * (size_t)node + 2] - cz;
        *reinterpret_cast<float3*>(out + ((size_t)w * Lp1 + hl) * 3) = v;
      }
      if (hl + 32 < Lp1) {
        const int node = seqr1;
        float3 v;
        v.x = xb[3 * (size_t)node + 0] - cx;
        v.y = xb[3 * (size_t)node + 1] - cy;
        v.z = xb[3 * (size_t)node + 2] - cz;
        *reinterpret_cast<float3*>(out + ((size_t)w * Lp1 + hl + 32) * 3) = v;
      }
    }
  } else {
    // ============ global-chase fallback (verified R5/R8 logic) ============
    // Two walks per wave, run SEQUENTIALLY with the full-wave code verbatim.
    for (int sub = 0; sub < 2; ++sub) {
      const int w = w0 + 2 * wv + sub;
      if (w >= num_walks) continue;          // wave-uniform
      const int bb = w / G;
      const int* __restrict__ nbG = nbrs + (size_t)bb * N * 3;
      const float* __restrict__ xb = xyz + (size_t)bb * N * 3;
      const int f0 = centers[w];
      const uint32_t mka = visL[((2 * wv + sub) * CH + lane) * 2 + 0];
      const uint32_t mkb = visL[((2 * wv + sub) * CH + lane) * 2 + 1];
      uint32_t mycode;
      {
        uint32_t k1a, k1b, hi, lo;
        tf2x32(mka, mkb, 0u, 1u, k1a, k1b);
        randbits(k1a, k1b, hi, lo);
        mycode = pick_code(hi, lo);
      }
      uint32_t extka = 0, extkb = 0;
      int extc = -1;
      auto get_key = [&](int idxk, uint32_t& ra, uint32_t& rb) {
        if (idxk < CH) {
          ra = (uint32_t)__shfl((int)mka, idxk);
          rb = (uint32_t)__shfl((int)mkb, idxk);
        } else {
          if (extc < 0) {
            extka = (uint32_t)__shfl((int)mka, CH - 1);
            extkb = (uint32_t)__shfl((int)mkb, CH - 1);
            extc = CH - 1;
          }
          while (extc < idxk) { tf2x32(extka, extkb, 0u, 0u, extka, extkb); ++extc; }
          ra = extka; rb = extkb;
        }
      };

      int seqr = (lane == 0) ? f0 : -1;
      uint32_t code_next = (uint32_t)__shfl((int)mycode, 0);
      int i = 1, bs = 1, c = 0;
      int hist  = (lane == 0) ? f0 : -1;
      int hist2 = -1;
      int3 row = *reinterpret_cast<const int3*>(nbG + 3 * (size_t)f0);
      while (i <= L) {
        const int idx = c; ++c;
        const bool deep = (idx >= CH);
        const uint32_t codeP = code_next;
        code_next = (uint32_t)__shfl((int)mycode, (c < CH) ? c : 0);

        const int n0 = row.x, n1 = row.y, n2 = row.z;
        int v0 = __any(hist == n0), v1 = __any(hist == n1), v2 = __any(hist == n2);
        if (deep) {
          v0 |= __any(hist2 == n0); v1 |= __any(hist2 == n1); v2 |= __any(hist2 == n2);
        }
        const int u0 = 1 - v0, u1 = 1 - v1, u2 = 1 - v2;
        const int cnt = u0 + u1 + u2;

        int to_add;
        bool hit = false;
        int bsf = bs;
        if (cnt > 0) {
          uint32_t code = codeP;
          if (deep) {
            uint32_t ia, ib, k1a, k1b, hi, lo;
            get_key(idx, ia, ib);
            tf2x32(ia, ib, 0u, 1u, k1a, k1b);
            randbits(k1a, k1b, hi, lo);
            code = pick_code(hi, lo);
          }
          const int r3 = (int)(code & 3u), r2 = (int)((code >> 2) & 1u);
          const int target = (cnt == 3 ? r3 : (cnt == 2 ? r2 : 0)) + 1;
          to_add = (u0 == target) ? n0 : ((u0 + u1 == target) ? n1 : n2);
        } else {
          uint32_t kia, kib;
          get_key(idx, kia, kib);
          uint32_t kka, kkb;
          tf2x32(kia, kib, 0u, 2u, kka, kkb);
          bool found = false;
          int ta = 0, bsc = bs;
          while (!found && i > bsc) {
            uint32_t ca, cb, kpa, kpb;
            tf2x32(kka, kkb, 0u, 0u, ca, cb);
            tf2x32(kka, kkb, 0u, 1u, kpa, kpb);
            const int back = __shfl(seqr, i - bsc - 1);
            const int3 br = *reinterpret_cast<const int3*>(nbG + 3 * (size_t)back);
            int w0m = __any(hist == br.x), w1m = __any(hist == br.y), w2m = __any(hist == br.z);
            if (deep) {
              w0m |= __any(hist2 == br.x); w1m |= __any(hist2 == br.y); w2m |= __any(hist2 == br.z);
            }
            const int e0 = 1 - w0m, e1 = 1 - w1m, e2 = 1 - w2m;
            const int bc = e0 + e1 + e2;
            if (bc > 0) {
              uint32_t bhi, blo;
              randbits(kpa, kpb, bhi, blo);
              const uint32_t bcode = pick_code(bhi, blo);
              const int r3 = (int)(bcode & 3u), r2 = (int)((bcode >> 2) & 1u);
              const int t2v = (bc == 3 ? r3 : (bc == 2 ? r2 : 0)) + 1;
              ta = (e0 == t2v) ? br.x : ((e0 + e1 == t2v) ? br.y : br.z);
              found = true;
            } else {
              bsc += 2;
            }
            kka = ca; kkb = cb;
          }
          if (found) {
            to_add = ta; hit = true; bsf = bsc;
          } else {
            uint32_t k3a, k3b, rhi, rlo;
            tf2x32(kia, kib, 0u, 3u, k3a, k3b);
            randbits(k3a, k3b, rhi, rlo);
            to_add = (int)r_generic(rhi, rlo, (uint32_t)N);
          }
        }

        int i_new, up;
        if (hit) { i_new = i - bsf; bs = bsf; up = i - 1; }
        else     { i_new = i;       bs = 1;   up = i; }
        seqr = (lane >= i_new && lane <= up) ? to_add : seqr;

        const int slot = idx + 1;
        if (slot < CH)          hist  = (lane == slot)      ? to_add : hist;
        else if (slot < 2 * CH) hist2 = (lane == slot - CH) ? to_add : hist2;

        i = i_new + 1;
        row = *reinterpret_cast<const int3*>(nbG + 3 * (size_t)to_add);
      }

      const float cx = xb[3 * (size_t)f0 + 0];
      const float cy = xb[3 * (size_t)f0 + 1];
      const float cz = xb[3 * (size_t)f0 + 2];
      if (lane < Lp1) {
        const int node = seqr;
        float3 v;
        v.x = xb[3 * (size_t)node + 0] - cx;
        v.y = xb[3 * (size_t)node + 1] - cy;
        v.z = xb[3 * (size_t)node + 2] - cz;
        *reinterpret_cast<float3*>(out + ((size_t)w * Lp1 + lane) * 3) = v;
      }
    }
  }
}

}  // namespace

extern "C" void kernel_launch(void* const* d_in, const int* in_sizes, int n_in,
                              void* d_out, int out_size, void* d_ws, size_t ws_size,
                              hipStream_t stream) {
  const float* xyz     = (const float*)d_in[0];
  const int*   nbrs    = (const int*)d_in[1];
  const int*   centers = (const int*)d_in[2];
  const int*   n_faces = (const int*)d_in[3];
  const int*   seq_len = (const int*)d_in[4];
  float* out = (float*)d_out;

  const int s0 = in_sizes[0];                  // B*N*3
  const int num_walks = in_sizes[2];           // B*G
  const int Lp1 = out_size / (3 * num_walks);  // seq_len+1

  const int blocks = (num_walks + WPB - 1) / WPB;
  walk_kernel<<<blocks, WAVES * 64, 0, stream>>>(
      xyz, nbrs, centers, n_faces, seq_len, out, s0, num_walks, Lp1);
}